// Round 5
// baseline (339.389 us; speedup 1.0000x reference)
//
#include <hip/hip_runtime.h>
#include <math.h>

#define L3 2197            // 13^3
#define SP 2200            // bf16 elems per padded volume (4400 B, 16B-aligned)
#define NV (SP / 8)        // 275 uint4 chunks of 8 bf16
#define NTW 64             // ONE WAVE per volume: no inter-wave barriers at all
#define NTO 320            // k_out: gather-only kernel, single-pass over 275 chunks

// In-place smooth peak = 13*17*17 = 3757 floats (17^3 never materialized:
// M_a is fused with C_a). 3760*4 = 15040 B -> 10 blocks/CU LDS-capped.
#define SSZ 3760

typedef unsigned int u32;

// round-to-nearest-even bf16 pack of two floats -> one u32 (lo = a, hi = b)
__device__ __forceinline__ u32 pack2bf(float a, float b) {
    u32 ua = __float_as_uint(a);
    u32 ub = __float_as_uint(b);
    ua = (ua + 0x7fffu + ((ua >> 16) & 1u)) >> 16;
    ub = (ub + 0x7fffu + ((ub >> 16) & 1u)) & 0xffff0000u;
    return ua | ub;
}

__device__ __forceinline__ void unpack8(uint4 v, float* f) {
    f[0] = __uint_as_float(v.x << 16);
    f[1] = __uint_as_float(v.x & 0xffff0000u);
    f[2] = __uint_as_float(v.y << 16);
    f[3] = __uint_as_float(v.y & 0xffff0000u);
    f[4] = __uint_as_float(v.z << 16);
    f[5] = __uint_as_float(v.z & 0xffff0000u);
    f[6] = __uint_as_float(v.w << 16);
    f[7] = __uint_as_float(v.w & 0xffff0000u);
}

__device__ __forceinline__ uint4 pack8(const float* f) {
    uint4 v;
    v.x = pack2bf(f[0], f[1]);
    v.y = pack2bf(f[2], f[3]);
    v.z = pack2bf(f[4], f[5]);
    v.w = pack2bf(f[6], f[7]);
    return v;
}

// Sliding clamped max-of-3 (edge-pad 3 + maxpool3 VALID): x[13] -> o[17]
__device__ __forceinline__ void maxpool_row(const float* x, float* o) {
    float p[12];
#pragma unroll
    for (int i = 0; i < 12; ++i) p[i] = fmaxf(x[i], x[i + 1]);
    o[0] = x[0];
    o[1] = x[0];
    o[2] = p[0];
#pragma unroll
    for (int j = 3; j <= 13; ++j) o[j] = fmaxf(p[j - 3], x[j - 1]);
    o[14] = p[11];
    o[15] = x[12];
    o[16] = x[12];
}

// Two stacked avgpool3 == 5-tap triangle [1,2,3,2,1] (scale applied): y[17] -> o[13]
__device__ __forceinline__ void tri_row(const float* y, float* o, float scale) {
#pragma unroll
    for (int c = 0; c < 13; ++c) {
        float s = fmaf(2.0f, y[c + 1], y[c]);
        s = fmaf(3.0f, y[c + 2], s);
        s = fmaf(2.0f, y[c + 3], s);
        o[c] = (s + y[c + 4]) * scale;
    }
}

// Single-wave in-place smooth. S holds (13,13,13); on return S[0..2196]=smooth(S).
// Stages: M_c, M_b, (M_a+C_a fused), C_b, C_c — each done in 64-pencil chunks.
// Cross-chunk write/read hazards are impossible given chunk ORDER:
//   expansion stages (M_c, M_b: write above read) -> DESCENDING chunks;
//   contraction stages (C_b, C_c: write below read) -> ASCENDING chunks.
//   (same-a collisions fall in disjoint c mod 17 classes; different-a are range-
//    separated.)
// Within-chunk cross-lane hazards: all chunk ds_reads precede all chunk ds_writes
// in program order (sched_barrier(0) pins the compiler; the per-wave LDS pipe is
// in-order). M_a+C_a is column-exclusive per lane: no fence needed.
__device__ void smooth_wave(float* S, const int lane) {
    __syncthreads();   // make caller's fill ordered/visible
    // M_c along c: (13,13,13) -> (13,13,17); 169 pencils: read 13 @ p*13, write 17 @ p*17
#pragma unroll
    for (int cb = 2; cb >= 0; --cb) {          // DESC
        const int p = cb * 64 + lane;
        const bool act = p < 169;
        float x[13], o[17];
        if (act) {
            const float* s = S + p * 13;
#pragma unroll
            for (int i = 0; i < 13; ++i) x[i] = s[i];
            maxpool_row(x, o);
        }
        __builtin_amdgcn_sched_barrier(0);
        if (act) {
            float* d = S + p * 17;
#pragma unroll
            for (int i = 0; i < 17; ++i) d[i] = o[i];
        }
        __builtin_amdgcn_sched_barrier(0);
    }
    __syncthreads();
    // M_b along b: (13,13,17) -> (13,17,17); 221 pencils (a=p/17, c=p%17)
#pragma unroll
    for (int cb = 3; cb >= 0; --cb) {          // DESC
        const int p = cb * 64 + lane;
        const bool act = p < 221;
        const int a = p / 17, c = p % 17;
        float x[13], o[17];
        if (act) {
            const float* s = S + a * 221 + c;
#pragma unroll
            for (int i = 0; i < 13; ++i) x[i] = s[i * 17];
            maxpool_row(x, o);
        }
        __builtin_amdgcn_sched_barrier(0);
        if (act) {
            float* d = S + a * 289 + c;
#pragma unroll
            for (int i = 0; i < 17; ++i) d[i * 17] = o[i];
        }
        __builtin_amdgcn_sched_barrier(0);
    }
    __syncthreads();
    // M_a + C_a fused: per (b,c) column (stride 289), exclusively owned by lane
#pragma unroll
    for (int cb = 0; cb < 5; ++cb) {
        const int p = cb * 64 + lane;
        if (p < 289) {
            float x[13], m[17], o[13];
            const float* s = S + p;
#pragma unroll
            for (int i = 0; i < 13; ++i) x[i] = s[i * 289];
            maxpool_row(x, m);
            tri_row(m, o, 1.0f);
            float* d = S + p;
#pragma unroll
            for (int i = 0; i < 13; ++i) d[i * 289] = o[i];
        }
    }
    __syncthreads();
    // C_b along b: (13,17,17) -> (13,13,17); 221 pencils
#pragma unroll
    for (int cb = 0; cb < 4; ++cb) {           // ASC
        const int p = cb * 64 + lane;
        const bool act = p < 221;
        const int a = p / 17, c = p % 17;
        float y[17], o[13];
        if (act) {
            const float* s = S + a * 289 + c;
#pragma unroll
            for (int i = 0; i < 17; ++i) y[i] = s[i * 17];
            tri_row(y, o, 1.0f);
        }
        __builtin_amdgcn_sched_barrier(0);
        if (act) {
            float* d = S + a * 221 + c;
#pragma unroll
            for (int i = 0; i < 13; ++i) d[i * 17] = o[i];
        }
        __builtin_amdgcn_sched_barrier(0);
    }
    __syncthreads();
    // C_c along c: (13,13,17) -> (13,13,13); 169 pencils, scale 1/729
#pragma unroll
    for (int cb = 0; cb < 3; ++cb) {           // ASC
        const int p = cb * 64 + lane;
        const bool act = p < 169;
        float y[17], o[13];
        if (act) {
            const float* s = S + p * 17;
#pragma unroll
            for (int i = 0; i < 17; ++i) y[i] = s[i];
            tri_row(y, o, 1.0f / 729.0f);
        }
        __builtin_amdgcn_sched_barrier(0);
        if (act) {
            float* d = S + p * 13;
#pragma unroll
            for (int i = 0; i < 13; ++i) d[i] = o[i];
        }
        __builtin_amdgcn_sched_barrier(0);
    }
    __syncthreads();
}

// Batched neighbor prologue: 8 unconditional index/dist loads (clamped in-row),
// weights zeroed for k >= K. All uniform scalar loads.
__device__ __forceinline__ void load_nbr_meta(
        const int* __restrict__ knn, const float* __restrict__ dist,
        int n, int K, int* idx, float* wk, float* norm_out) {
    float dv[8];
#pragma unroll
    for (int k = 0; k < 8; ++k) {
        const int kc = (k < K) ? k : (K - 1);
        idx[k] = knn[n * K + kc];
        dv[k] = dist[n * K + kc];
    }
    float norm = 0.0f;
#pragma unroll
    for (int k = 0; k < 8; ++k) {
        float w = (k < K) ? expf(-dv[k] * (1.0f / 200.0f)) : 0.0f;
        wk[k] = w;
        norm += w;
    }
    *norm_out = norm;
}

// tmp1 = smooth(a1 + a0*cost) as bf16; preA = a4 + a2*(a1 + a0*cost) as bf16
__global__ __launch_bounds__(NTW) void k_smooth1(
        const float* __restrict__ cost, const float* __restrict__ alpha,
        uint4* __restrict__ tmp1, uint4* __restrict__ preA) {
    __shared__ alignas(16) float S[SSZ];
    const int n = blockIdx.x;
    const int lane = threadIdx.x;
    const float a0 = alpha[0], a1 = alpha[1], a2 = alpha[2], a4 = alpha[4];
    const float* src = cost + (size_t)n * L3;
    for (int i = lane; i < L3; i += NTW) S[i] = fmaf(a0, src[i], a1);
    if (lane < SP - L3) S[L3 + lane] = 0.0f;   // pad for preA pack loop
    __syncthreads();
    uint4* pre = preA + (size_t)n * NV;
#pragma unroll
    for (int r = 0; r < 5; ++r) {
        const int i = r * 64 + lane;
        if (i < NV) {
            float f[8];
#pragma unroll
            for (int j = 0; j < 8; ++j) f[j] = fmaf(a2, S[8 * i + j], a4);
            pre[i] = pack8(f);
        }
    }
    smooth_wave(S, lane);
    uint4* dst = tmp1 + (size_t)n * NV;
#pragma unroll
    for (int r = 0; r < 5; ++r) {
        const int i = r * 64 + lane;
        if (i < NV) {
            float f[8];
            const int base = 8 * i;
#pragma unroll
            for (int j = 0; j < 8; ++j) f[j] = (base + j < L3) ? S[base + j] : 0.0f;
            dst[i] = pack8(f);
        }
    }
}

// tmp2 = smooth(preA + (a3/norm) * sum_k w_k * tmp1[knn_k]) as bf16
__global__ __launch_bounds__(NTW) void k_mid(
        const int* __restrict__ knn, const float* __restrict__ dist,
        const float* __restrict__ alpha, const uint4* __restrict__ tmp1,
        const uint4* __restrict__ preA, uint4* __restrict__ tmp2, int K) {
    __shared__ alignas(16) float S[SSZ];
    const int n = blockIdx.x;
    const int lane = threadIdx.x;
    int idx[8];
    float wk[8], norm;
    load_nbr_meta(knn, dist, n, K, idx, wk, &norm);
    const float sc = alpha[3] / norm;

    const uint4* pre = preA + (size_t)n * NV;
    const uint4* nb[8];
#pragma unroll
    for (int k = 0; k < 8; ++k)
        nb[k] = tmp1 + (size_t)__builtin_amdgcn_readfirstlane(idx[k]) * NV;

    // 275 chunks over 64 lanes: 5 rounds, 2-deep load pipeline (loads clamped,
    // stores predicated) so round r+1's 9 dwordx4 loads fly under round r's math.
    uint4 av[9], bv[9];
    {
        const int i = lane;                    // < 275 always
        av[8] = pre[i];
#pragma unroll
        for (int k = 0; k < 8; ++k) av[k] = nb[k][i];
    }
#pragma unroll
    for (int r = 0; r < 5; ++r) {
        if (r < 4) {
            const int i = (r + 1) * 64 + lane;
            const int ic = (i < NV) ? i : (NV - 1);
            bv[8] = pre[ic];
#pragma unroll
            for (int k = 0; k < 8; ++k) bv[k] = nb[k][ic];
        }
        const int i = r * 64 + lane;
        if (i < NV) {
            float f[8], acc[8], g[8];
            unpack8(av[8], f);
#pragma unroll
            for (int j = 0; j < 8; ++j) acc[j] = 0.0f;
#pragma unroll
            for (int k = 0; k < 8; ++k) {
                unpack8(av[k], g);
#pragma unroll
                for (int j = 0; j < 8; ++j) acc[j] = fmaf(wk[k], g[j], acc[j]);
            }
#pragma unroll
            for (int j = 0; j < 8; ++j) S[8 * i + j] = fmaf(sc, acc[j], f[j]);
        }
#pragma unroll
        for (int q = 0; q < 9; ++q) av[q] = bv[q];
    }
    smooth_wave(S, lane);
    uint4* dst = tmp2 + (size_t)n * NV;
#pragma unroll
    for (int r = 0; r < 5; ++r) {
        const int i = r * 64 + lane;
        if (i < NV) {
            float f[8];
            const int base = 8 * i;
#pragma unroll
            for (int j = 0; j < 8; ++j) f[j] = (base + j < L3) ? S[base + j] : 0.0f;
            dst[i] = pack8(f);
        }
    }
}

// out = (a5/norm) * sum_k w_k * tmp2[knn_k]   (fp32 output)
__global__ __launch_bounds__(NTO) void k_out(
        const int* __restrict__ knn, const float* __restrict__ dist,
        const float* __restrict__ alpha, const uint4* __restrict__ tmp2,
        float* __restrict__ out, int K) {
    const int n = blockIdx.x;
    const int tid = threadIdx.x;
    int idx[8];
    float wk[8], norm;
    load_nbr_meta(knn, dist, n, K, idx, wk, &norm);
    const float sc = alpha[5] / norm;

    float* dst = out + (size_t)n * L3;
    if (tid < NV) {
        uint4 v[8];
#pragma unroll
        for (int k = 0; k < 8; ++k) {
            const size_t b = (size_t)__builtin_amdgcn_readfirstlane(idx[k]) * NV;
            v[k] = tmp2[b + tid];
        }
        float acc[8], g[8];
#pragma unroll
        for (int j = 0; j < 8; ++j) acc[j] = 0.0f;
#pragma unroll
        for (int k = 0; k < 8; ++k) {
            unpack8(v[k], g);
#pragma unroll
            for (int j = 0; j < 8; ++j) acc[j] = fmaf(wk[k], g[j], acc[j]);
        }
        const int base = 8 * tid;
#pragma unroll
        for (int j = 0; j < 8; ++j)
            if (base + j < L3) dst[base + j] = sc * acc[j];
    }
}

extern "C" void kernel_launch(void* const* d_in, const int* in_sizes, int n_in,
                              void* d_out, int out_size, void* d_ws, size_t ws_size,
                              hipStream_t stream) {
    const float* cost  = (const float*)d_in[0];
    const int*   knn   = (const int*)d_in[1];
    const float* dist  = (const float*)d_in[2];
    const float* alpha = (const float*)d_in[3];
    float* out = (float*)d_out;

    const int N = in_sizes[0] / L3;
    int K = in_sizes[1] / N;
    if (K > 8) K = 8;

    // workspace: three bf16 volume arrays, each N*NV uint4 (N*4400 bytes)
    uint4* tmp1 = (uint4*)d_ws;
    uint4* tmp2 = tmp1 + (size_t)N * NV;
    uint4* preA = tmp2 + (size_t)N * NV;

    k_smooth1<<<N, NTW, 0, stream>>>(cost, alpha, tmp1, preA);
    k_mid<<<N, NTW, 0, stream>>>(knn, dist, alpha, tmp1, preA, tmp2, K);
    k_out<<<N, NTO, 0, stream>>>(knn, dist, alpha, tmp2, out, K);
}

// Round 7
// 330.998 us; speedup vs baseline: 1.0254x; 1.0254x over previous
//
#include <hip/hip_runtime.h>
#include <math.h>

#define L3 2197            // 13^3
#define SP 2200            // bf16 elems per padded volume (4400 B, 16B-aligned)
#define NV (SP / 8)        // 275 uint4 chunks of 8 bf16
#define NTW 64             // ONE WAVE per volume: per-wave ordering, no inter-wave sync
#define NTO 320            // k_out: gather-only kernel, single-pass over 275 chunks

// Padded-stride in-place smooth buffer.
// Layouts inside S (floats):  A1[a][b][c] = a*234 + b*18 + c   (13,13,17 +pad c=17)
//                             A2[a][b'][c] = a*306 + b'*18 + c (13,17,17 +pad c=17)
//                             S2[m] = m (2200, final contiguous)
// Peak = A2 extent 3978 -> 3984 floats (15936 B) -> 10 blocks/CU LDS-capped.
#define SSZ 3984

typedef unsigned int u32;

// round-to-nearest-even bf16 pack of two floats -> one u32 (lo = a, hi = b)
__device__ __forceinline__ u32 pack2bf(float a, float b) {
    u32 ua = __float_as_uint(a);
    u32 ub = __float_as_uint(b);
    ua = (ua + 0x7fffu + ((ua >> 16) & 1u)) >> 16;
    ub = (ub + 0x7fffu + ((ub >> 16) & 1u)) & 0xffff0000u;
    return ua | ub;
}

__device__ __forceinline__ void unpack8(uint4 v, float* f) {
    f[0] = __uint_as_float(v.x << 16);
    f[1] = __uint_as_float(v.x & 0xffff0000u);
    f[2] = __uint_as_float(v.y << 16);
    f[3] = __uint_as_float(v.y & 0xffff0000u);
    f[4] = __uint_as_float(v.z << 16);
    f[5] = __uint_as_float(v.z & 0xffff0000u);
    f[6] = __uint_as_float(v.w << 16);
    f[7] = __uint_as_float(v.w & 0xffff0000u);
}

__device__ __forceinline__ uint4 pack8(const float* f) {
    uint4 v;
    v.x = pack2bf(f[0], f[1]);
    v.y = pack2bf(f[2], f[3]);
    v.z = pack2bf(f[4], f[5]);
    v.w = pack2bf(f[6], f[7]);
    return v;
}

// Sliding clamped max-of-3 (edge-pad 3 + maxpool3 VALID): x[13] -> o[17]
__device__ __forceinline__ void maxpool_row(const float* x, float* o) {
    float p[12];
#pragma unroll
    for (int i = 0; i < 12; ++i) p[i] = fmaxf(x[i], x[i + 1]);
    o[0] = x[0];
    o[1] = x[0];
    o[2] = p[0];
#pragma unroll
    for (int j = 3; j <= 13; ++j) o[j] = fmaxf(p[j - 3], x[j - 1]);
    o[14] = p[11];
    o[15] = x[12];
    o[16] = x[12];
}

// Two stacked avgpool3 == 5-tap triangle [1,2,3,2,1] (scale applied): y[17] -> o[13]
__device__ __forceinline__ void tri_row(const float* y, float* o, float scale) {
#pragma unroll
    for (int c = 0; c < 13; ++c) {
        float s = fmaf(2.0f, y[c + 1], y[c]);
        s = fmaf(3.0f, y[c + 2], s);
        s = fmaf(2.0f, y[c + 3], s);
        o[c] = (s + y[c + 4]) * scale;
    }
}

// Single-wave in-place smooth, c-pair (float2) vectorized.
// If gsrc != nullptr, M_c reads global applying ga*x+gb; else reads S2 LDS input.
// On return S[0..2196] = smooth, S[2197..2199] = 0.
// Ordering framework (validated on HW in r5): DESC chunks for expansion stages,
// ASC for contraction; sched_barrier(0) pins within-chunk reads before writes;
// per-wave LDS pipe is in-order. The c=17 pad column is garbage that never
// mixes with real columns (all ops are per-column elementwise).
__device__ void smooth_wave2(float* S, const int lane,
                             const float* __restrict__ gsrc, float ga, float gb) {
    __syncthreads();
    // M_c along c: in(13p) -> A1 row(18p); 169 pencils. DESC (in-place expand).
    //   cross-chunk safe: 18p >= 18p'+18 > 13p'+12 for p > p'.
#pragma unroll
    for (int cb = 2; cb >= 0; --cb) {
        const int p = cb * 64 + lane;
        const bool act = p < 169;
        float x[13], o[17];
        if (act) {
            if (gsrc != nullptr) {   // wave-uniform branch
#pragma unroll
                for (int i = 0; i < 13; ++i) x[i] = fmaf(ga, gsrc[p * 13 + i], gb);
            } else {
#pragma unroll
                for (int i = 0; i < 13; ++i) x[i] = S[p * 13 + i];
            }
            maxpool_row(x, o);
        }
        __builtin_amdgcn_sched_barrier(0);
        if (act) {
            float* row = S + p * 18;          // 18p even -> 8B-aligned pairs
#pragma unroll
            for (int j = 0; j < 8; ++j)
                *(float2*)(row + 2 * j) = make_float2(o[2 * j], o[2 * j + 1]);
            row[16] = o[16];
        }
        __builtin_amdgcn_sched_barrier(0);
    }
    __syncthreads();
    // M_b along b: A1 -> A2; 117 c-pair units (a = q/9, cp = q%9). DESC.
    //   a' < a: read max 234a'+233 < 306a write min; a'=a: disjoint cols mod 18.
#pragma unroll
    for (int cb = 1; cb >= 0; --cb) {
        const int q = cb * 64 + lane;
        const bool act = q < 117;
        const int a = q / 9, cp = q % 9;
        float xl[13], xh[13], ol[17], oh[17];
        if (act) {
            const float* s = S + a * 234 + 2 * cp;
#pragma unroll
            for (int i = 0; i < 13; ++i) {
                float2 v = *(const float2*)(s + i * 18);
                xl[i] = v.x; xh[i] = v.y;
            }
            maxpool_row(xl, ol);
            maxpool_row(xh, oh);
        }
        __builtin_amdgcn_sched_barrier(0);
        if (act) {
            float* d = S + a * 306 + 2 * cp;
#pragma unroll
            for (int i = 0; i < 17; ++i)
                *(float2*)(d + i * 18) = make_float2(ol[i], oh[i]);
        }
        __builtin_amdgcn_sched_barrier(0);
    }
    __syncthreads();
    // M_a + C_a fused: A2 columns along a (stride 306); 153 pair-units (bp,cp),
    // column-exclusive per lane -> no fences needed.
#pragma unroll
    for (int cb = 0; cb < 3; ++cb) {
        const int r = cb * 64 + lane;
        if (r < 153) {
            const int bp = r / 9, cp = r % 9;
            float* colp = S + bp * 18 + 2 * cp;
            float xl[13], xh[13], ml[17], mh[17], ol[13], oh[13];
#pragma unroll
            for (int i = 0; i < 13; ++i) {
                float2 v = *(const float2*)(colp + i * 306);
                xl[i] = v.x; xh[i] = v.y;
            }
            maxpool_row(xl, ml);
            tri_row(ml, ol, 1.0f);
            maxpool_row(xh, mh);
            tri_row(mh, oh, 1.0f);
#pragma unroll
            for (int i = 0; i < 13; ++i)
                *(float2*)(colp + i * 306) = make_float2(ol[i], oh[i]);
        }
    }
    __syncthreads();
    // C_b along b: A2 -> A1; 117 pair units. ASC.
    //   a' > a: read min 306a' > 234a+233 write max; a'=a: disjoint cols mod 18.
#pragma unroll
    for (int cb = 0; cb < 2; ++cb) {
        const int q = cb * 64 + lane;
        const bool act = q < 117;
        const int a = q / 9, cp = q % 9;
        float yl[17], yh[17], ol[13], oh[13];
        if (act) {
            const float* s = S + a * 306 + 2 * cp;
#pragma unroll
            for (int i = 0; i < 17; ++i) {
                float2 v = *(const float2*)(s + i * 18);
                yl[i] = v.x; yh[i] = v.y;
            }
            tri_row(yl, ol, 1.0f);
            tri_row(yh, oh, 1.0f);
        }
        __builtin_amdgcn_sched_barrier(0);
        if (act) {
            float* d = S + a * 234 + 2 * cp;
#pragma unroll
            for (int i = 0; i < 13; ++i)
                *(float2*)(d + i * 18) = make_float2(ol[i], oh[i]);
        }
        __builtin_amdgcn_sched_barrier(0);
    }
    __syncthreads();
    // C_c along c: A1 row(18p) -> S2(13p); 169 pencils, 1/729. ASC.
    //   later reads at 18p' >= 18p+18 > 13p+12 write max.
#pragma unroll
    for (int cb = 0; cb < 3; ++cb) {
        const int p = cb * 64 + lane;
        const bool act = p < 169;
        float y[17], o[13];
        if (act) {
            const float* row = S + p * 18;
#pragma unroll
            for (int j = 0; j < 8; ++j) {
                float2 v = *(const float2*)(row + 2 * j);
                y[2 * j] = v.x; y[2 * j + 1] = v.y;
            }
            y[16] = row[16];
            tri_row(y, o, 1.0f / 729.0f);
        }
        __builtin_amdgcn_sched_barrier(0);
        if (act) {
            float* d = S + p * 13;
#pragma unroll
            for (int i = 0; i < 13; ++i) d[i] = o[i];
        }
        __builtin_amdgcn_sched_barrier(0);
    }
    if (lane < SP - L3) S[L3 + lane] = 0.0f;   // zero pad for aligned pack reads
    __syncthreads();
}

// Batched neighbor prologue: 8 unconditional index/dist loads (clamped in-row),
// weights zeroed for k >= K. All uniform scalar loads.
__device__ __forceinline__ void load_nbr_meta(
        const int* __restrict__ knn, const float* __restrict__ dist,
        int n, int K, int* idx, float* wk, float* norm_out) {
    float dv[8];
#pragma unroll
    for (int k = 0; k < 8; ++k) {
        const int kc = (k < K) ? k : (K - 1);
        idx[k] = knn[n * K + kc];
        dv[k] = dist[n * K + kc];
    }
    float norm = 0.0f;
#pragma unroll
    for (int k = 0; k < 8; ++k) {
        float w = (k < K) ? expf(-dv[k] * (1.0f / 200.0f)) : 0.0f;
        wk[k] = w;
        norm += w;
    }
    *norm_out = norm;
}

// tmp1 = smooth(a1 + a0*cost) as bf16; preA = a4 + a2*(a1 + a0*cost) as bf16
__global__ __launch_bounds__(NTW) void k_smooth1(
        const float* __restrict__ cost, const float* __restrict__ alpha,
        uint4* __restrict__ tmp1, uint4* __restrict__ preA) {
    __shared__ alignas(16) float S[SSZ];
    const int n = blockIdx.x;
    const int lane = threadIdx.x;
    const float a0 = alpha[0], a1 = alpha[1], a2 = alpha[2], a4 = alpha[4];
    const float* src = cost + (size_t)n * L3;

    // preA: pure global->global, no LDS; issued first so loads overlap smooth
    uint4* pre = preA + (size_t)n * NV;
#pragma unroll
    for (int r = 0; r < 5; ++r) {
        const int t = r * 64 + lane;
        if (t < NV) {
            float f[8];
#pragma unroll
            for (int j = 0; j < 8; ++j) {
                const int m = 8 * t + j;
                const float c = (m < L3) ? src[m] : 0.0f;
                f[j] = fmaf(a2, fmaf(a0, c, a1), a4);
            }
            pre[t] = pack8(f);
        }
    }

    smooth_wave2(S, lane, src, a0, a1);

    uint4* dst = tmp1 + (size_t)n * NV;
    const float4* Sv = (const float4*)S;
#pragma unroll
    for (int r = 0; r < 5; ++r) {
        const int t = r * 64 + lane;
        if (t < NV) {
            float4 f0 = Sv[2 * t], f1 = Sv[2 * t + 1];
            float f[8] = {f0.x, f0.y, f0.z, f0.w, f1.x, f1.y, f1.z, f1.w};
            dst[t] = pack8(f);
        }
    }
}

// tmp2 = smooth(preA + (a3/norm) * sum_k w_k * tmp1[knn_k]) as bf16
__global__ __launch_bounds__(NTW) void k_mid(
        const int* __restrict__ knn, const float* __restrict__ dist,
        const float* __restrict__ alpha, const uint4* __restrict__ tmp1,
        const uint4* __restrict__ preA, uint4* __restrict__ tmp2, int K) {
    __shared__ alignas(16) float S[SSZ];
    const int n = blockIdx.x;
    const int lane = threadIdx.x;
    int idx[8];
    float wk[8], norm;
    load_nbr_meta(knn, dist, n, K, idx, wk, &norm);
    const float sc = alpha[3] / norm;

    const uint4* pre = preA + (size_t)n * NV;
    const uint4* nb[8];
#pragma unroll
    for (int k = 0; k < 8; ++k)
        nb[k] = tmp1 + (size_t)__builtin_amdgcn_readfirstlane(idx[k]) * NV;

    // 275 chunks over 64 lanes: 5 rounds, 2-deep load pipeline (loads clamped,
    // stores predicated) so round r+1's 9 dwordx4 loads fly under round r's math.
    float4* Sw = (float4*)S;
    uint4 av[9], bv[9];
    {
        const int i = lane;                    // < 275 always
        av[8] = pre[i];
#pragma unroll
        for (int k = 0; k < 8; ++k) av[k] = nb[k][i];
    }
#pragma unroll
    for (int r = 0; r < 5; ++r) {
        if (r < 4) {
            const int i = (r + 1) * 64 + lane;
            const int ic = (i < NV) ? i : (NV - 1);
            bv[8] = pre[ic];
#pragma unroll
            for (int k = 0; k < 8; ++k) bv[k] = nb[k][ic];
        }
        const int i = r * 64 + lane;
        if (i < NV) {
            float f[8], acc[8], g[8];
            unpack8(av[8], f);
#pragma unroll
            for (int j = 0; j < 8; ++j) acc[j] = 0.0f;
#pragma unroll
            for (int k = 0; k < 8; ++k) {
                unpack8(av[k], g);
#pragma unroll
                for (int j = 0; j < 8; ++j) acc[j] = fmaf(wk[k], g[j], acc[j]);
            }
            float rle[8];
#pragma unroll
            for (int j = 0; j < 8; ++j) rle[j] = fmaf(sc, acc[j], f[j]);
            Sw[2 * i]     = make_float4(rle[0], rle[1], rle[2], rle[3]);
            Sw[2 * i + 1] = make_float4(rle[4], rle[5], rle[6], rle[7]);
        }
#pragma unroll
        for (int q = 0; q < 9; ++q) av[q] = bv[q];
    }
    smooth_wave2(S, lane, nullptr, 0.0f, 0.0f);
    uint4* dst = tmp2 + (size_t)n * NV;
    const float4* Sv = (const float4*)S;
#pragma unroll
    for (int r = 0; r < 5; ++r) {
        const int t = r * 64 + lane;
        if (t < NV) {
            float4 f0 = Sv[2 * t], f1 = Sv[2 * t + 1];
            float f[8] = {f0.x, f0.y, f0.z, f0.w, f1.x, f1.y, f1.z, f1.w};
            dst[t] = pack8(f);
        }
    }
}

// out = (a5/norm) * sum_k w_k * tmp2[knn_k]   (fp32 output)
__global__ __launch_bounds__(NTO) void k_out(
        const int* __restrict__ knn, const float* __restrict__ dist,
        const float* __restrict__ alpha, const uint4* __restrict__ tmp2,
        float* __restrict__ out, int K) {
    const int n = blockIdx.x;
    const int tid = threadIdx.x;
    int idx[8];
    float wk[8], norm;
    load_nbr_meta(knn, dist, n, K, idx, wk, &norm);
    const float sc = alpha[5] / norm;

    float* dst = out + (size_t)n * L3;
    if (tid < NV) {
        uint4 v[8];
#pragma unroll
        for (int k = 0; k < 8; ++k) {
            const size_t b = (size_t)__builtin_amdgcn_readfirstlane(idx[k]) * NV;
            v[k] = tmp2[b + tid];
        }
        float acc[8], g[8];
#pragma unroll
        for (int j = 0; j < 8; ++j) acc[j] = 0.0f;
#pragma unroll
        for (int k = 0; k < 8; ++k) {
            unpack8(v[k], g);
#pragma unroll
            for (int j = 0; j < 8; ++j) acc[j] = fmaf(wk[k], g[j], acc[j]);
        }
        const int base = 8 * tid;
#pragma unroll
        for (int j = 0; j < 8; ++j)
            if (base + j < L3) dst[base + j] = sc * acc[j];
    }
}

extern "C" void kernel_launch(void* const* d_in, const int* in_sizes, int n_in,
                              void* d_out, int out_size, void* d_ws, size_t ws_size,
                              hipStream_t stream) {
    const float* cost  = (const float*)d_in[0];
    const int*   knn   = (const int*)d_in[1];
    const float* dist  = (const float*)d_in[2];
    const float* alpha = (const float*)d_in[3];
    float* out = (float*)d_out;

    const int N = in_sizes[0] / L3;
    int K = in_sizes[1] / N;
    if (K > 8) K = 8;

    // workspace: three bf16 volume arrays, each N*NV uint4 (N*4400 bytes)
    uint4* tmp1 = (uint4*)d_ws;
    uint4* tmp2 = tmp1 + (size_t)N * NV;
    uint4* preA = tmp2 + (size_t)N * NV;

    k_smooth1<<<N, NTW, 0, stream>>>(cost, alpha, tmp1, preA);
    k_mid<<<N, NTW, 0, stream>>>(knn, dist, alpha, tmp1, preA, tmp2, K);
    k_out<<<N, NTO, 0, stream>>>(knn, dist, alpha, tmp2, out, K);
}